// Round 19
// baseline (156.421 us; speedup 1.0000x reference)
//
#include <hip/hip_runtime.h>
#include <hip/hip_bf16.h>

#define NB 16
#define SEQ 2048
#define EDIM 256

typedef __attribute__((ext_vector_type(4)))  float f32x4;
typedef __attribute__((ext_vector_type(8)))  short short8;

static __device__ __forceinline__ ushort f2bf(float f) {
    uint32_t u = __float_as_uint(f);
    uint32_t r = (u + 0x7fffu + ((u >> 16) & 1u)) >> 16;
    return (ushort)r;
}
static __device__ __forceinline__ float bf2f(ushort h) {
    return __uint_as_float(((uint32_t)h) << 16);
}
// async global->LDS, 16 bytes per lane; LDS dest wave-uniform, global src per-lane.
static __device__ __forceinline__ void gll16(const ushort* g, ushort* l) {
    __builtin_amdgcn_global_load_lds(
        (const __attribute__((address_space(1))) uint32_t*)g,
        (__attribute__((address_space(3))) uint32_t*)l,
        16, 0, 0);
}
// raw barrier: lgkm-only wait, never drains in-flight vmem stores
static __device__ __forceinline__ void lgkm_barrier() {
    asm volatile("s_waitcnt lgkmcnt(0)" ::: "memory");
    __builtin_amdgcn_sched_barrier(0);
    __builtin_amdgcn_s_barrier();
    asm volatile("" ::: "memory");
}

// Kernel 1: fp32 -> bf16 in K-MAJOR PANEL layout xb[b][ks][t][j] (ks=e>>4,
// j=e&15), plus per-row sum of squares of the bf16-rounded values.
__global__ void prep_kernel(const float* __restrict__ x,
                            ushort* __restrict__ xb,
                            float* __restrict__ sq) {
    __shared__ ushort sh[4][256];
    const int tid  = threadIdx.x;
    const int r    = tid >> 6;
    const int lane = tid & 63;
    const int grow = blockIdx.x * 4;
    const int row  = grow + r;

    const f32x4* xp = reinterpret_cast<const f32x4*>(x + (size_t)row * EDIM + lane * 4);
    const f32x4 v = __builtin_nontemporal_load(xp);
    ushort h0 = f2bf(v.x), h1 = f2bf(v.y), h2 = f2bf(v.z), h3 = f2bf(v.w);
    ushort4 h; h.x = h0; h.y = h1; h.z = h2; h.w = h3;
    *reinterpret_cast<ushort4*>(&sh[r][lane * 4]) = h;

    const float fx = bf2f(h0), fy = bf2f(h1), fz = bf2f(h2), fw = bf2f(h3);
    float s = fx * fx + fy * fy + fz * fz + fw * fw;
    #pragma unroll
    for (int m = 1; m < 64; m <<= 1) s += __shfl_xor(s, m);
    if (lane == 0) sq[row] = s;

    __syncthreads();

    const int b   = grow >> 11;
    const int t0  = grow & 2047;
    const int ksx = tid >> 4;
    const int idx = tid & 15;
    const int r2  = idx >> 2;
    const int j   = (idx & 3) * 4;
    ushort4 o = *reinterpret_cast<ushort4*>(&sh[r2][ksx * 16 + j]);
    *reinterpret_cast<ushort4*>(xb + (size_t)b * SEQ * EDIM
                                   + (size_t)ksx * SEQ * 16
                                   + (size_t)(t0 + r2) * 16 + j) = o;
}

// Kernel 2: fused gram-GEMM + one-pass softmax, 16-ROW blocks for 2 WG/CU
// co-residency (the untested overlap mechanism: CU scheduler interleaves one
// WG's store phase with the other's GEMM; no same-wave load/store interleave,
// so the R8/R13/R16 inflation pattern is avoided). 1024 thr, 16 waves; wave
// owns 128 cols; mfma_f32_16x16x32_bf16 -> acc = 32 regs; launch_bounds
// (1024,8) forces <=64 total regs. LDS 73.3 KB -> 2 WGs fit. 4 blocks/WG,
// grid (16,32). Laws kept: plain stores, separate burst phase, counted
// vmcnt(8) at block top, no stores in K-loop.
__global__ __launch_bounds__(1024, 8) void sims_main(
        const ushort* __restrict__ xb,
        const float*  __restrict__ sq,
        float* __restrict__ out) {
    __shared__ __align__(16) ushort AB[4096];       // 8 KB: [ks8][64 chunks][8]
    __shared__ __align__(16) float Tr[8][2048];     // 64 KB transpose buffer
    __shared__ float red[16][17];
    __shared__ float inv_s[16];

    const int b    = blockIdx.x;        // batch -> XCD = flat%8 = b%8
    const int g    = blockIdx.y;        // rows [g*64,(g+1)*64), 4 blocks of 16
    const int tid  = threadIdx.x;
    const int wave = tid >> 6;          // 0..15
    const int lane = tid & 63;
    const int l15  = lane & 15;
    const int q4   = lane >> 4;         // 0..3

    const ushort* xbB = xb + (size_t)b * SEQ * EDIM;
    const float*  sqB = sq + b * SEQ;
    float* outB = out + (size_t)b * SEQ * SEQ;

    const int colw = wave * 128;
    // B frag: col = colw + cb*16 + l15; k = q4*8 + j (K=32 -> ks16 = 2*ks8 + (q4>>1))
    const ushort* bbase = xbB + ((size_t)(colw + l15)) * 16
                              + (size_t)(q4 >> 1) * (SEQ * 16) + (q4 & 1) * 8;
    // A stage (waves 0..7, ks8 = wave): lane λ holds chunk (r=λ>>2, c=(λ&3)^((r>>1)&3))
    const int ar = lane >> 2;
    const int ac = (lane & 3) ^ ((ar >> 1) & 3);
    // A read position: chunk (r=l15, c=q4) lives at q = r*4 + (c ^ ((r>>1)&3))
    const int pq = l15 * 4 + (q4 ^ ((l15 >> 1) & 3));

    constexpr float kC   = (float)(-1.4426950408889634 / 13.544);  // -log2(e)/T
    constexpr float m2kC = -2.0f * kC;

    // prologue: stage A for block 0
    if (wave < 8) {
        gll16(xbB + (size_t)(2 * wave + (ac >> 1)) * (SEQ * 16)
                  + (size_t)(g * 64 + ar) * 16 + (ac & 1) * 8,
              AB + wave * 512);
    }

    const int row8 = wave >> 1;          // burst: row within 8-row chunk
    const int half = wave & 1;           // which 4KB half of the row

    #pragma unroll 1
    for (int rb = 0; rb < 4; ++rb) {
        if (rb == 0) { asm volatile("s_waitcnt vmcnt(0)" ::: "memory"); }
        else         { asm volatile("s_waitcnt vmcnt(8)" ::: "memory"); }
        __builtin_amdgcn_sched_barrier(0);
        __builtin_amdgcn_s_barrier();
        __builtin_amdgcn_sched_barrier(0);

        const int row_base = g * 64 + rb * 16;

        f32x4 acc[8];
        #pragma unroll
        for (int cb = 0; cb < 8; ++cb) acc[cb] = (f32x4)0.0f;

        #pragma unroll 2
        for (int ks8 = 0; ks8 < 8; ++ks8) {
            const ushort* bks = bbase + (size_t)ks8 * (2 * SEQ * 16);
            const short8 a = *reinterpret_cast<const short8*>(AB + ks8 * 512 + pq * 8);
            // half-split to cap live registers
            short8 bv[4];
            #pragma unroll
            for (int cb = 0; cb < 4; ++cb)
                bv[cb] = *reinterpret_cast<const short8*>(bks + cb * 256);
            #pragma unroll
            for (int cb = 0; cb < 4; ++cb)
                acc[cb] = __builtin_amdgcn_mfma_f32_16x16x32_bf16(a, bv[cb], acc[cb], 0, 0, 0);
            #pragma unroll
            for (int cb = 0; cb < 4; ++cb)
                bv[cb] = *reinterpret_cast<const short8*>(bks + (cb + 4) * 256);
            #pragma unroll
            for (int cb = 0; cb < 4; ++cb)
                acc[cb + 4] = __builtin_amdgcn_mfma_f32_16x16x32_bf16(a, bv[cb], acc[cb + 4], 0, 0, 0);
        }

        // ---- epilogue: exp(-dist/T), row sums (rows = q4*4 + reg) ----
        float part[4];
        #pragma unroll
        for (int reg = 0; reg < 4; ++reg) {
            const float kcr = kC * sqB[row_base + q4 * 4 + reg];
            float p = 0.0f;
            #pragma unroll
            for (int cb = 0; cb < 8; ++cb) {
                const float t = fmaf(kC, sqB[colw + cb * 16 + l15], kcr);
                const float e = exp2f(fmaf(m2kC, acc[cb][reg], t));
                acc[cb][reg] = e;
                p += e;
            }
            p += __shfl_xor(p, 1);
            p += __shfl_xor(p, 2);
            p += __shfl_xor(p, 4);
            p += __shfl_xor(p, 8);
            part[reg] = p;
        }
        if (l15 == 0) {                  // lanes 0,16,32,48
            #pragma unroll
            for (int reg = 0; reg < 4; ++reg)
                red[q4 * 4 + reg][wave] = part[reg];
        }
        lgkm_barrier();                  // all waves past K-loop: AB free

        // restage A for next block (issued before this block's stores)
        if (rb < 3 && wave < 8) {
            gll16(xbB + (size_t)(2 * wave + (ac >> 1)) * (SEQ * 16)
                      + (size_t)(row_base + 16 + ar) * 16 + (ac & 1) * 8,
                  AB + wave * 512);
        }
        if (tid < 16) {
            float s = 0.0f;
            #pragma unroll
            for (int w = 0; w < 16; ++w) s += red[tid][w];
            inv_s[tid] = 1.0f / s;
        }
        lgkm_barrier();

        // ---- 2 chunks of 8 rows: deposit (swizzled) then burst ----
        #pragma unroll 1
        for (int ch = 0; ch < 2; ++ch) {
            if ((q4 >> 1) == ch) {       // rows q4*4+reg are in this chunk
                const int rloc = (q4 & 1) * 4;   // + reg
                #pragma unroll
                for (int reg = 0; reg < 4; ++reg) {
                    const float scale = inv_s[ch * 8 + rloc + reg];
                    const int bx = (((rloc + reg) >> 2) & 1) << 4;   // bank-split
                    #pragma unroll
                    for (int cb = 0; cb < 8; ++cb)
                        Tr[rloc + reg][(colw + cb * 16 + l15) ^ bx] = acc[cb][reg] * scale;
                }
            }
            lgkm_barrier();
            const int bx = ((row8 >> 2) & 1) << 4;
            float* orow = outB + (size_t)(row_base + ch * 8 + row8) * SEQ + half * 1024;
            #pragma unroll
            for (int j = 0; j < 4; ++j) {
                const f32x4 v = *reinterpret_cast<const f32x4*>(
                    &Tr[row8][(half * 1024 + j * 256 + lane * 4) ^ bx]);
                *reinterpret_cast<f32x4*>(&orow[j * 256 + lane * 4]) = v;  // plain store
            }
            lgkm_barrier();              // Tr consumed; stores keep flying
        }
    }
}

extern "C" void kernel_launch(void* const* d_in, const int* in_sizes, int n_in,
                              void* d_out, int out_size, void* d_ws, size_t ws_size,
                              hipStream_t stream) {
    (void)in_sizes; (void)n_in; (void)out_size; (void)ws_size;
    const float* x = (const float*)d_in[0];
    float* out = (float*)d_out;

    ushort* xb = (ushort*)d_ws;                                       // 16 MB bf16, k-major panels
    float*  sq = (float*)((char*)d_ws + (size_t)NB * SEQ * EDIM * 2); // 128 KB row norms

    prep_kernel<<<NB * SEQ / 4, 256, 0, stream>>>(x, xb, sq);

    dim3 grid(NB, 32);   // x = batch: flat%8 == batch%8 -> XCD locality; 512 WGs = 2/CU
    sims_main<<<grid, 1024, 0, stream>>>(xb, sq, out);
}